// Round 1
// baseline (465.483 us; speedup 1.0000x reference)
//
#include <hip/hip_runtime.h>
#include <hip/hip_bf16.h>

#define B_   8
#define SQ_  2048
#define SK_  2048
#define D_   128

typedef __attribute__((ext_vector_type(8))) _Float16 f16x8;
typedef __attribute__((ext_vector_type(4))) float    f32x4;

__device__ __forceinline__ f16x8 load_cvt8(const float* p) {
    f32x4 a = *(const f32x4*)p;
    f32x4 b = *(const f32x4*)(p + 4);
    f16x8 r;
    r[0] = (_Float16)a[0]; r[1] = (_Float16)a[1];
    r[2] = (_Float16)a[2]; r[3] = (_Float16)a[3];
    r[4] = (_Float16)b[0]; r[5] = (_Float16)b[1];
    r[6] = (_Float16)b[2]; r[7] = (_Float16)b[3];
    return r;
}

// ---------------------------------------------------------------------------
// Kernel 1: rz[q][k] = 1 / sum_b exp( (Q[b,q,:] . K[b,k,:]) / 128 )
// grid (SK/64, SQ/64), block 512 (8 waves, wave = batch)
// ---------------------------------------------------------------------------
__global__ __launch_bounds__(512)
void zk(const float* __restrict__ Q, const float* __restrict__ K,
        _Float16* __restrict__ rz) {
    __shared__ float Zbuf[64 * 64];

    const int kt   = blockIdx.x * 64;
    const int qt   = blockIdx.y * 64;
    const int b    = threadIdx.x >> 6;     // wave index = batch
    const int lane = threadIdx.x & 63;
    const int row  = lane & 15;
    const int koff = (lane >> 4) * 8;

    for (int i = threadIdx.x; i < 64 * 64; i += 512) Zbuf[i] = 0.0f;
    __syncthreads();

    const float* Qb = Q + (size_t)b * SQ_ * D_;
    const float* Kb = K + (size_t)b * SK_ * D_;

    f32x4 acc[4][4] = {};
#pragma unroll
    for (int ks = 0; ks < 4; ++ks) {
        f16x8 af[4], bfr[4];
#pragma unroll
        for (int mt = 0; mt < 4; ++mt)
            af[mt] = load_cvt8(Qb + (size_t)(qt + mt * 16 + row) * D_ + ks * 32 + koff);
#pragma unroll
        for (int nt = 0; nt < 4; ++nt)
            bfr[nt] = load_cvt8(Kb + (size_t)(kt + nt * 16 + row) * D_ + ks * 32 + koff);
#pragma unroll
        for (int mt = 0; mt < 4; ++mt)
#pragma unroll
            for (int nt = 0; nt < 4; ++nt)
                acc[mt][nt] = __builtin_amdgcn_mfma_f32_16x16x32_f16(
                    af[mt], bfr[nt], acc[mt][nt], 0, 0, 0);
    }

    const int qr = (lane >> 4) * 4;   // D-layout: row = (l>>4)*4 + r
    const int kc = lane & 15;         //           col = l & 15
#pragma unroll
    for (int mt = 0; mt < 4; ++mt)
#pragma unroll
        for (int nt = 0; nt < 4; ++nt)
#pragma unroll
            for (int r = 0; r < 4; ++r) {
                float e = __expf(acc[mt][nt][r] * (1.0f / 128.0f));
                atomicAdd(&Zbuf[(mt * 16 + qr + r) * 64 + nt * 16 + kc], e);
            }
    __syncthreads();

    // write reciprocal Z, 512 threads x 8 elements, coalesced 16B stores
    const int idx = threadIdx.x * 8;
    const int qq  = idx >> 6;
    const int kk  = idx & 63;
    f16x8 o;
#pragma unroll
    for (int j = 0; j < 8; ++j) o[j] = (_Float16)(1.0f / Zbuf[idx + j]);
    *(f16x8*)(rz + (size_t)(qt + qq) * SK_ + kt + kk) = o;
}

// ---------------------------------------------------------------------------
// Kernel 2: out[b,qt..qt+31,:] = sum_k (exp(S)/Z) * V
// grid (SQ/32, B), block 512 (8 waves; wave w owns ktiles w, w+8, ...)
// ---------------------------------------------------------------------------
__global__ __launch_bounds__(512)
void avk(const float* __restrict__ Q, const float* __restrict__ K,
         const float* __restrict__ V, const _Float16* __restrict__ rz,
         float* __restrict__ out) {
    __shared__ __attribute__((aligned(16))) _Float16 Pbuf[8][32][40];
    __shared__ __attribute__((aligned(16))) _Float16 Vt[8][128][40];
    __shared__ float Obuf[32 * 128];

    const int qt   = blockIdx.x * 32;
    const int b    = blockIdx.y;
    const int w    = threadIdx.x >> 6;
    const int lane = threadIdx.x & 63;
    const int row  = lane & 15;
    const int koff = (lane >> 4) * 8;

    for (int i = threadIdx.x; i < 32 * 128; i += 512) Obuf[i] = 0.0f;

    const float* Qb = Q + (size_t)b * SQ_ * D_;
    const float* Kb = K + (size_t)b * SK_ * D_;
    const float* Vb = V + (size_t)b * SK_ * D_;

    // preload Q fragments for this 32-row q-tile
    f16x8 qf[2][4];
#pragma unroll
    for (int mt = 0; mt < 2; ++mt)
#pragma unroll
        for (int ks = 0; ks < 4; ++ks)
            qf[mt][ks] = load_cvt8(Qb + (size_t)(qt + mt * 16 + row) * D_ + ks * 32 + koff);

    f32x4 oacc[2][8] = {};
    const int qr = (lane >> 4) * 4;
    const int kc = lane & 15;
    const int vk = lane & 31;          // V-stage: k within tile
    const int vd = (lane >> 5) * 64;   // V-stage: d half

    for (int j = 0; j < 8; ++j) {
        const int k0 = (j * 8 + w) * 32;

        // S = Q K^T (32x32) for this wave's k-tile
        f32x4 sacc[2][2] = {};
#pragma unroll
        for (int ks = 0; ks < 4; ++ks) {
            f16x8 bfr[2];
#pragma unroll
            for (int nt = 0; nt < 2; ++nt)
                bfr[nt] = load_cvt8(Kb + (size_t)(k0 + nt * 16 + row) * D_ + ks * 32 + koff);
#pragma unroll
            for (int mt = 0; mt < 2; ++mt)
#pragma unroll
                for (int nt = 0; nt < 2; ++nt)
                    sacc[mt][nt] = __builtin_amdgcn_mfma_f32_16x16x32_f16(
                        qf[mt][ks], bfr[nt], sacc[mt][nt], 0, 0, 0);
        }

        // P = exp(S/128) * rz  -> Pbuf (D-layout scatter, wave-private)
#pragma unroll
        for (int mt = 0; mt < 2; ++mt)
#pragma unroll
            for (int nt = 0; nt < 2; ++nt)
#pragma unroll
                for (int r = 0; r < 4; ++r) {
                    int qq = mt * 16 + qr + r;
                    int kk = nt * 16 + kc;
                    float rzv = (float)rz[(size_t)(qt + qq) * SK_ + k0 + kk];
                    float p = __expf(sacc[mt][nt][r] * (1.0f / 128.0f)) * rzv;
                    Pbuf[w][qq][kk] = (_Float16)p;
                }

        // stage V^T: Vt[d][k] (wave-private tile)
#pragma unroll
        for (int dj = 0; dj < 64; dj += 4) {
            f32x4 v = *(const f32x4*)(Vb + (size_t)(k0 + vk) * D_ + vd + dj);
            Vt[w][vd + dj + 0][vk] = (_Float16)v[0];
            Vt[w][vd + dj + 1][vk] = (_Float16)v[1];
            Vt[w][vd + dj + 2][vk] = (_Float16)v[2];
            Vt[w][vd + dj + 3][vk] = (_Float16)v[3];
        }
        __syncthreads();

        // O += P @ V   (M=32, N=128, K=32)
        f16x8 pf[2];
#pragma unroll
        for (int mt = 0; mt < 2; ++mt)
            pf[mt] = *(const f16x8*)&Pbuf[w][mt * 16 + row][koff];
#pragma unroll
        for (int nt = 0; nt < 8; ++nt) {
            f16x8 vf = *(const f16x8*)&Vt[w][nt * 16 + row][koff];
#pragma unroll
            for (int mt = 0; mt < 2; ++mt)
                oacc[mt][nt] = __builtin_amdgcn_mfma_f32_16x16x32_f16(
                    pf[mt], vf, oacc[mt][nt], 0, 0, 0);
        }
        __syncthreads();
    }

    // reduce partial O across the 8 waves
#pragma unroll
    for (int mt = 0; mt < 2; ++mt)
#pragma unroll
        for (int nt = 0; nt < 8; ++nt)
#pragma unroll
            for (int r = 0; r < 4; ++r)
                atomicAdd(&Obuf[(mt * 16 + qr + r) * 128 + nt * 16 + kc],
                          oacc[mt][nt][r]);
    __syncthreads();

    // coalesced write-out
    const int idx = threadIdx.x * 8;
    const int qq  = idx >> 7;
    const int dd  = idx & 127;
    float* op = out + ((size_t)b * SQ_ + qt + qq) * D_ + dd;
    *(f32x4*)op       = *(f32x4*)&Obuf[idx];
    *(f32x4*)(op + 4) = *(f32x4*)&Obuf[idx + 4];
}

// ---------------------------------------------------------------------------
extern "C" void kernel_launch(void* const* d_in, const int* in_sizes, int n_in,
                              void* d_out, int out_size, void* d_ws, size_t ws_size,
                              hipStream_t stream) {
    const float* Q = (const float*)d_in[0];
    const float* K = (const float*)d_in[1];
    const float* V = (const float*)d_in[2];
    float* out = (float*)d_out;
    _Float16* rz = (_Float16*)d_ws;   // 2048*2048*2B = 8.39 MB scratch

    zk<<<dim3(SK_ / 64, SQ_ / 64), 512, 0, stream>>>(Q, K, rz);
    avk<<<dim3(SQ_ / 32, B_), 512, 0, stream>>>(Q, K, V, rz, out);
}

// Round 2
// 279.906 us; speedup vs baseline: 1.6630x; 1.6630x over previous
//
#include <hip/hip_runtime.h>
#include <hip/hip_bf16.h>

#define B_   8
#define SQ_  2048
#define SK_  2048
#define D_   128
#define KSPLIT 4
#define KT_PER 16   // (SK_/32)/KSPLIT k-tiles per block

typedef __attribute__((ext_vector_type(8))) _Float16 f16x8;
typedef __attribute__((ext_vector_type(4))) float    f32x4;

// ---------------------------------------------------------------------------
// fp32 -> f16 elementwise convert (Q, K)
// ---------------------------------------------------------------------------
__global__ __launch_bounds__(256)
void cvt16(const float* __restrict__ s, _Float16* __restrict__ d) {
    int i = blockIdx.x * 256 + threadIdx.x;
    f32x4 a = *(const f32x4*)(s + (size_t)i * 8);
    f32x4 b = *(const f32x4*)(s + (size_t)i * 8 + 4);
    f16x8 r;
    r[0] = (_Float16)a[0]; r[1] = (_Float16)a[1];
    r[2] = (_Float16)a[2]; r[3] = (_Float16)a[3];
    r[4] = (_Float16)b[0]; r[5] = (_Float16)b[1];
    r[6] = (_Float16)b[2]; r[7] = (_Float16)b[3];
    *(f16x8*)(d + (size_t)i * 8) = r;
}

// ---------------------------------------------------------------------------
// V[b][k][d] fp32  ->  Vt[b][d][k] f16   (tile 64k x 128d per block)
// ---------------------------------------------------------------------------
__global__ __launch_bounds__(256)
void vtrans(const float* __restrict__ V, _Float16* __restrict__ Vt) {
    __shared__ _Float16 T[128][72];
    const int b  = blockIdx.y;
    const int k0 = blockIdx.x * 64;
    const int t  = threadIdx.x;
    const int kl = t >> 2;          // 0..63
    const int d0 = (t & 3) * 32;    // 0,32,64,96

    const float* src = V + ((size_t)b * SK_ + k0 + kl) * D_ + d0;
#pragma unroll
    for (int u = 0; u < 32; u += 4) {
        f32x4 v = *(const f32x4*)(src + u);
        T[d0 + u + 0][kl] = (_Float16)v[0];
        T[d0 + u + 1][kl] = (_Float16)v[1];
        T[d0 + u + 2][kl] = (_Float16)v[2];
        T[d0 + u + 3][kl] = (_Float16)v[3];
    }
    __syncthreads();
    const int dr = t >> 1;          // 0..127
    const int kh = (t & 1) * 32;    // 0,32
    _Float16* dst = Vt + ((size_t)b * D_ + dr) * SK_ + k0 + kh;
#pragma unroll
    for (int u = 0; u < 32; u += 8)
        *(f16x8*)(dst + u) = *(const f16x8*)&T[dr][kh + u];
}

// ---------------------------------------------------------------------------
// Fused kernel: block = 8 waves, wave = batch, q-tile 16, k-slice SK/KSPLIT.
// Cross-batch softmax denom via LDS atomicAdd (double-buffered Z).
// out accumulated with global fp32 atomicAdd (out pre-zeroed).
// ---------------------------------------------------------------------------
__global__ __launch_bounds__(512, 4)
void fused(const _Float16* __restrict__ Qh, const _Float16* __restrict__ Kh,
           const _Float16* __restrict__ Vt, float* __restrict__ out) {
    __shared__ float Zbuf[2][512];
    __shared__ __attribute__((aligned(16))) _Float16 Pbuf[8][16][40];

    // XCD-aware decode: blockIdx round-robins XCDs (bid%8 = XCD), so pin
    // each XCD to ONE k-slice -> its f16 K/V slice (2.1 MB) fits 4MB L2.
    const int bid = blockIdx.x;
    const int xcd = bid & 7;
    const int kb  = xcd & 3;                        // k-slice 0..3
    const int qi  = (bid >> 3) * 2 + (xcd >> 2);    // q-tile 0..127
    const int qt  = qi * 16;

    const int b    = threadIdx.x >> 6;   // wave = batch
    const int lane = threadIdx.x & 63;
    const int row  = lane & 15;
    const int koff = (lane >> 4) * 8;
    const int qr   = (lane >> 4) * 4;    // D-layout row group
    const int kc   = lane & 15;          // D-layout col

    Zbuf[0][threadIdx.x] = 0.0f;
    Zbuf[1][threadIdx.x] = 0.0f;

    const _Float16* Qb = Qh + (size_t)b * SQ_ * D_;
    const _Float16* Kb = Kh + (size_t)b * SK_ * D_;
    const _Float16* Vb = Vt + (size_t)b * D_ * SK_;

    f16x8 qf[4];
#pragma unroll
    for (int ks = 0; ks < 4; ++ks)
        qf[ks] = *(const f16x8*)(Qb + (size_t)(qt + row) * D_ + ks * 32 + koff);

    f32x4 oacc[8] = {};
    __syncthreads();

    for (int j = 0; j < KT_PER; ++j) {
        const int kt = (kb * KT_PER + j) * 32;
        const int p  = j & 1;

        // S = Q K^T  (16 x 32), K = 128
        f32x4 sacc[2] = {};
#pragma unroll
        for (int ks = 0; ks < 4; ++ks) {
            f16x8 k0f = *(const f16x8*)(Kb + (size_t)(kt + row) * D_ + ks * 32 + koff);
            f16x8 k1f = *(const f16x8*)(Kb + (size_t)(kt + 16 + row) * D_ + ks * 32 + koff);
            sacc[0] = __builtin_amdgcn_mfma_f32_16x16x32_f16(qf[ks], k0f, sacc[0], 0, 0, 0);
            sacc[1] = __builtin_amdgcn_mfma_f32_16x16x32_f16(qf[ks], k1f, sacc[1], 0, 0, 0);
        }

        // e = exp(S/128); Z[q][k] += e across the 8 batches (waves)
        float e[8];
#pragma unroll
        for (int nt = 0; nt < 2; ++nt)
#pragma unroll
            for (int r = 0; r < 4; ++r) {
                float ev = __expf(sacc[nt][r] * (1.0f / 128.0f));
                e[nt * 4 + r] = ev;
                atomicAdd(&Zbuf[p][(qr + r) * 32 + nt * 16 + kc], ev);
            }
        __syncthreads();

        // P = e / Z  -> Pbuf (wave-private); zero the other Z buffer
#pragma unroll
        for (int nt = 0; nt < 2; ++nt)
#pragma unroll
            for (int r = 0; r < 4; ++r) {
                float z = Zbuf[p][(qr + r) * 32 + nt * 16 + kc];
                float pv = e[nt * 4 + r] * __builtin_amdgcn_rcpf(z);
                Pbuf[b][qr + r][nt * 16 + kc] = (_Float16)pv;
            }
        Zbuf[p ^ 1][threadIdx.x] = 0.0f;

        // O += P @ V  (M=16, N=128, K=32), V fragments direct from global Vt
        f16x8 pf = *(const f16x8*)&Pbuf[b][row][koff];
#pragma unroll
        for (int nt = 0; nt < 8; ++nt) {
            f16x8 vf = *(const f16x8*)(Vb + (size_t)(nt * 16 + row) * SK_ + kt + koff);
            oacc[nt] = __builtin_amdgcn_mfma_f32_16x16x32_f16(pf, vf, oacc[nt], 0, 0, 0);
        }
        __syncthreads();
    }

    // accumulate partial O into out (pre-zeroed); lanes 0-15 cover 64B rows
#pragma unroll
    for (int nt = 0; nt < 8; ++nt)
#pragma unroll
        for (int r = 0; r < 4; ++r)
            atomicAdd(&out[((size_t)b * SQ_ + qt + qr + r) * D_ + nt * 16 + kc],
                      oacc[nt][r]);
}

// ---------------------------------------------------------------------------
extern "C" void kernel_launch(void* const* d_in, const int* in_sizes, int n_in,
                              void* d_out, int out_size, void* d_ws, size_t ws_size,
                              hipStream_t stream) {
    const float* Q = (const float*)d_in[0];
    const float* K = (const float*)d_in[1];
    const float* V = (const float*)d_in[2];
    float* out = (float*)d_out;

    const size_t tensor_elems = (size_t)B_ * SQ_ * D_;        // 2,097,152
    _Float16* Qh = (_Float16*)d_ws;
    _Float16* Kh = Qh + tensor_elems;
    _Float16* Vt = Kh + tensor_elems;                         // total 12.6 MB

    hipMemsetAsync(out, 0, tensor_elems * sizeof(float), stream);

    const int n8 = (int)(tensor_elems / 8);                   // 262144
    cvt16<<<n8 / 256, 256, 0, stream>>>(Q, Qh);
    cvt16<<<n8 / 256, 256, 0, stream>>>(K, Kh);
    vtrans<<<dim3(SK_ / 64, B_), 256, 0, stream>>>(V, Vt);

    fused<<<dim3(128 * KSPLIT), 512, 0, stream>>>(Qh, Kh, Vt, out);
}

// Round 3
// 171.866 us; speedup vs baseline: 2.7084x; 1.6286x over previous
//
#include <hip/hip_runtime.h>
#include <hip/hip_bf16.h>

#define B_   8
#define SQ_  2048
#define SK_  2048
#define D_   128

typedef __attribute__((ext_vector_type(8))) _Float16 f16x8;
typedef __attribute__((ext_vector_type(4))) _Float16 f16x4;
typedef __attribute__((ext_vector_type(4))) float    f32x4;

// Fragment-major layouts (all f16), lane = l, hi = l>>4, ql = l&15:
//  Qf[b][qt:128][ks:4][l:64][8] : elem (b, q = qt*16+ql, d = ks*32+hi*8+j)
//  Kf[b][kt:128][ks:4][l:64][8] : elem (b, k = kt*16+ql, d = ks*32+hi*8+j)
//  Vf[b][kt:128][dt:8][l:64][4] : elem (b, k = kt*16+hi*4+j, d = dt*16+ql)
//  RZ[qt:128][kt:128][l:64][4]  : elem (q = qt*16+ql, k = kt*16+hi*4+j)
#define QK_BSTRIDE (128 * 4 * 64 * 8)   // 262144 elems per batch
#define V_BSTRIDE  (128 * 8 * 64 * 4)   // 262144 elems per batch

// ---------------------------------------------------------------------------
// Q,K fp32 -> fragment-major f16.  grid (1024, 2), block 256.
// ---------------------------------------------------------------------------
__global__ __launch_bounds__(256)
void qkprep(const float* __restrict__ Q, const float* __restrict__ K,
            _Float16* __restrict__ Qf, _Float16* __restrict__ Kf) {
    const float* src = blockIdx.y ? K : Q;
    _Float16*    dst = blockIdx.y ? Kf : Qf;
    int gid = blockIdx.x * 256 + threadIdx.x;          // 0..262143
    int l  = gid & 63;
    int ks = (gid >> 6) & 3;
    int t  = (gid >> 8) & 127;
    int b  = gid >> 15;
    const float* p = src + ((size_t)b * 2048 + t * 16 + (l & 15)) * 128
                         + ks * 32 + (l >> 4) * 8;
    f32x4 a = *(const f32x4*)p;
    f32x4 c = *(const f32x4*)(p + 4);
    f16x8 r;
    r[0] = (_Float16)a[0]; r[1] = (_Float16)a[1];
    r[2] = (_Float16)a[2]; r[3] = (_Float16)a[3];
    r[4] = (_Float16)c[0]; r[5] = (_Float16)c[1];
    r[6] = (_Float16)c[2]; r[7] = (_Float16)c[3];
    *(f16x8*)(dst + (size_t)gid * 8) = r;
}

// ---------------------------------------------------------------------------
// V fp32 -> fragment-major f16 (transposed frags). grid (32, 8), block 256.
// ---------------------------------------------------------------------------
__global__ __launch_bounds__(256)
void vprep(const float* __restrict__ V, _Float16* __restrict__ Vf) {
    __shared__ _Float16 T[64][136];
    const int b  = blockIdx.y;
    const int kb = blockIdx.x;           // 64 k-rows per block
    const int t  = threadIdx.x;
    const int row = t >> 2, c0 = (t & 3) * 32;
    const float* src = V + ((size_t)b * SK_ + kb * 64 + row) * D_ + c0;
#pragma unroll
    for (int u = 0; u < 8; ++u) {
        f32x4 v = *(const f32x4*)(src + u * 4);
        f16x4 h;
        h[0] = (_Float16)v[0]; h[1] = (_Float16)v[1];
        h[2] = (_Float16)v[2]; h[3] = (_Float16)v[3];
        *(f16x4*)&T[row][c0 + u * 4] = h;
    }
    __syncthreads();
#pragma unroll
    for (int u = 0; u < 8; ++u) {
        int slot = t + 256 * u;          // 0..2047
        int l  = slot & 63;
        int dt = (slot >> 6) & 7;
        int kt = slot >> 9;              // 0..3
        int hi = l >> 4, ql = l & 15;
        f16x4 r;
#pragma unroll
        for (int j = 0; j < 4; ++j) r[j] = T[kt * 16 + hi * 4 + j][dt * 16 + ql];
        *(f16x4*)(Vf + ((((size_t)b * 128 + kb * 4 + kt) * 8 + dt) * 64 + l) * 4) = r;
    }
}

// ---------------------------------------------------------------------------
// Phase 1: rz[q][k] = 1 / sum_b exp(S_b[q,k]/128), fragment-major output.
// block = 8 waves = 8 batches, 64x64 tile. grid 1024, block 512.
// ---------------------------------------------------------------------------
__global__ __launch_bounds__(512, 4)
void zred(const _Float16* __restrict__ Qf, const _Float16* __restrict__ Kf,
          _Float16* __restrict__ RZ) {
    __shared__ _Float16 E[8][64][64];   // 64 KB, 16B-granule XOR swizzle
    const int bid   = blockIdx.x;
    const int qtile = bid >> 5, ktile = bid & 31;
    const int b  = threadIdx.x >> 6;
    const int l  = threadIdx.x & 63;
    const int hi = l >> 4, ql = l & 15;

    const _Float16* Qb = Qf + (size_t)b * QK_BSTRIDE;
    const _Float16* Kb = Kf + (size_t)b * QK_BSTRIDE;

    // swapped S^T = mfma(K, Q): D lane holds k = kk*16+hi*4+r, q = qq*16+ql
    f32x4 s[4][4] = {};
#pragma unroll
    for (int ks = 0; ks < 4; ++ks) {
        f16x8 kf[4];
#pragma unroll
        for (int kk = 0; kk < 4; ++kk)
            kf[kk] = *(const f16x8*)(Kb + ((((size_t)ktile * 4 + kk) * 4 + ks) * 64 + l) * 8);
#pragma unroll
        for (int qq = 0; qq < 4; ++qq) {
            f16x8 qv = *(const f16x8*)(Qb + ((((size_t)qtile * 4 + qq) * 4 + ks) * 64 + l) * 8);
#pragma unroll
            for (int kk = 0; kk < 4; ++kk)
                s[kk][qq] = __builtin_amdgcn_mfma_f32_16x16x32_f16(kf[kk], qv, s[kk][qq], 0, 0, 0);
        }
    }

    f16x4* E4 = (f16x4*)&E[0][0][0];
#pragma unroll
    for (int kk = 0; kk < 4; ++kk)
#pragma unroll
        for (int qq = 0; qq < 4; ++qq) {
            f16x4 e;
#pragma unroll
            for (int r = 0; r < 4; ++r)
                e[r] = (_Float16)__expf(s[kk][qq][r] * 0.0078125f);
            int q = qq * 16 + ql;
            int k = kk * 16 + hi * 4;
            int g16 = ((b * 64 + q) << 3) + ((k >> 3) ^ (q & 7));
            E4[g16 * 2 + ((k >> 2) & 1)] = e;
        }
    __syncthreads();

    // per-thread strip: q = t>>3 (0..63), k0 = (t&7)*8
    const int t  = threadIdx.x;
    const int q  = t >> 3, k0 = (t & 7) * 8;
    const f16x8* E8 = (const f16x8*)&E[0][0][0];
    const int gsw = (k0 >> 3) ^ (q & 7);
    f16x8 z = E8[(0 * 64 + q) * 8 + gsw];
#pragma unroll
    for (int bb = 1; bb < 8; ++bb)
        z = z + E8[(bb * 64 + q) * 8 + gsw];

    float inv[8];
#pragma unroll
    for (int j = 0; j < 8; ++j) inv[j] = __builtin_amdgcn_rcpf((float)z[j]);

    const int gq = qtile * 64 + q;
    const int gk = ktile * 64 + k0;
#pragma unroll
    for (int h = 0; h < 2; ++h) {
        int k   = gk + 4 * h;
        int kt  = k >> 4;
        int lh  = ((k & 15) >> 2) * 16 + (gq & 15);
        f16x4 rzv;
#pragma unroll
        for (int j = 0; j < 4; ++j) rzv[j] = (_Float16)inv[4 * h + j];
        *(f16x4*)(RZ + ((((size_t)(gq >> 4)) * 128 + kt) * 64 + lh) * 4) = rzv;
    }
}

// ---------------------------------------------------------------------------
// Phase 2: out[b] += (exp(S/128) * rz) @ V.  Independent waves, no LDS.
// wave = (qi 32 rows, b, k-slice of 256).  grid 512, block 512 (8 waves = 8 b).
// ---------------------------------------------------------------------------
__global__ __launch_bounds__(512, 3)
void av(const _Float16* __restrict__ Qf, const _Float16* __restrict__ Kf,
        const _Float16* __restrict__ Vf, const _Float16* __restrict__ RZ,
        float* __restrict__ out) {
    const int bid = blockIdx.x;          // 512
    const int ksl = bid & 7;             // k-slice -> XCD pinned
    const int qi  = bid >> 3;            // 0..63, 32 q-rows
    const int b   = threadIdx.x >> 6;
    const int l   = threadIdx.x & 63;
    const int hi  = l >> 4, ql = l & 15;

    const _Float16* Qb = Qf + (size_t)b * QK_BSTRIDE;
    const _Float16* Kb = Kf + (size_t)b * QK_BSTRIDE;
    const _Float16* Vb = Vf + (size_t)b * V_BSTRIDE;

    f16x8 qf[2][4];
#pragma unroll
    for (int qq = 0; qq < 2; ++qq)
#pragma unroll
        for (int ks = 0; ks < 4; ++ks)
            qf[qq][ks] = *(const f16x8*)(Qb + ((((size_t)qi * 2 + qq) * 4 + ks) * 64 + l) * 8);

    f32x4 oacc[2][8] = {};

    for (int it = 0; it < 8; ++it) {
        const int kt0 = ksl * 16 + it * 2;      // global 16-k tile base

        // S^T via swapped mfma: lane q = qq*16+ql, k = kk*16+hi*4+r
        f32x4 s[2][2] = {};
#pragma unroll
        for (int ks = 0; ks < 4; ++ks) {
            f16x8 k0 = *(const f16x8*)(Kb + ((((size_t)kt0 + 0) * 4 + ks) * 64 + l) * 8);
            f16x8 k1 = *(const f16x8*)(Kb + ((((size_t)kt0 + 1) * 4 + ks) * 64 + l) * 8);
#pragma unroll
            for (int qq = 0; qq < 2; ++qq) {
                s[0][qq] = __builtin_amdgcn_mfma_f32_16x16x32_f16(k0, qf[qq][ks], s[0][qq], 0, 0, 0);
                s[1][qq] = __builtin_amdgcn_mfma_f32_16x16x32_f16(k1, qf[qq][ks], s[1][qq], 0, 0, 0);
            }
        }

        // P fragment (16x16x16 A-layout) = exp(S/128) * rz — no repack needed
        f16x4 ph[2][2];
#pragma unroll
        for (int kk = 0; kk < 2; ++kk)
#pragma unroll
            for (int qq = 0; qq < 2; ++qq) {
                f16x4 rzv = *(const f16x4*)(RZ + ((((size_t)qi * 2 + qq) * 128 + kt0 + kk) * 64 + l) * 4);
                f16x4 p;
#pragma unroll
                for (int r = 0; r < 4; ++r)
                    p[r] = (_Float16)__expf(s[kk][qq][r] * 0.0078125f) * rzv[r];
                ph[qq][kk] = p;
            }

        // O += P @ V via 16x16x16 MFMA
#pragma unroll
        for (int dt = 0; dt < 8; ++dt) {
            f16x4 v0 = *(const f16x4*)(Vb + ((((size_t)kt0 + 0) * 8 + dt) * 64 + l) * 4);
            f16x4 v1 = *(const f16x4*)(Vb + ((((size_t)kt0 + 1) * 8 + dt) * 64 + l) * 4);
#pragma unroll
            for (int qq = 0; qq < 2; ++qq) {
                oacc[qq][dt] = __builtin_amdgcn_mfma_f32_16x16x16f16(ph[qq][0], v0, oacc[qq][dt], 0, 0, 0);
                oacc[qq][dt] = __builtin_amdgcn_mfma_f32_16x16x16f16(ph[qq][1], v1, oacc[qq][dt], 0, 0, 0);
            }
        }
    }

    // epilogue: D-layout row q = 4*hi + r, col d = dt*16 + ql
#pragma unroll
    for (int qq = 0; qq < 2; ++qq)
#pragma unroll
        for (int dt = 0; dt < 8; ++dt)
#pragma unroll
            for (int r = 0; r < 4; ++r)
                atomicAdd(&out[((size_t)b * SQ_ + qi * 32 + qq * 16 + hi * 4 + r) * D_
                               + dt * 16 + ql],
                          oacc[qq][dt][r]);
}

// ---------------------------------------------------------------------------
extern "C" void kernel_launch(void* const* d_in, const int* in_sizes, int n_in,
                              void* d_out, int out_size, void* d_ws, size_t ws_size,
                              hipStream_t stream) {
    const float* Q = (const float*)d_in[0];
    const float* K = (const float*)d_in[1];
    const float* V = (const float*)d_in[2];
    float* out = (float*)d_out;

    _Float16* Qf = (_Float16*)d_ws;                       // 4 MB
    _Float16* Kf = Qf + (size_t)B_ * QK_BSTRIDE;          // 4 MB
    _Float16* Vf = Kf + (size_t)B_ * QK_BSTRIDE;          // 4 MB
    _Float16* RZ = Vf + (size_t)B_ * V_BSTRIDE;           // 8 MB (21 MB total)

    hipMemsetAsync(out, 0, (size_t)B_ * SQ_ * D_ * sizeof(float), stream);

    qkprep<<<dim3(1024, 2), 256, 0, stream>>>(Q, K, Qf, Kf);
    vprep<<<dim3(32, B_), 256, 0, stream>>>(V, Vf);
    zred<<<1024, 512, 0, stream>>>(Qf, Kf, RZ);
    av<<<512, 512, 0, stream>>>(Qf, Kf, Vf, RZ, out);
}